// Round 1
// baseline (15994.788 us; speedup 1.0000x reference)
//
#include <hip/hip_runtime.h>

// ---------------------------------------------------------------------------
// 2-layer GRU, T=512, B=64, I=H=512, fp32.
// Persistent cooperative kernel: 256 WGs (1/CU) x 512 threads.
//   WGs 0..127  -> layer 1, step t = s
//   WGs 128..255-> layer 2, step t = s-1   (wavefront pipeline, 513 grid-steps)
// Per WG: 4 hidden cols (j0..j0+3) x 3 gates x 64 batch rows.
// 8 waves: wave = (side<<2)|kq ; side 0 = input-side GEMM (x or out1),
// side 1 = hidden-side GEMM; kq = K-quarter of 512. lane = batch row.
// Grid barrier: per-WG flag lines + generation word in d_ws.
// ---------------------------------------------------------------------------

#define GB_B 64
#define GB_H 512
#define GB_K 512
#define GB_G 1536
#define GB_T 512
#define NWG 256
#define NTHR 512

// float-word offsets inside ws
#define OFF_BUF1 0                       // [2][B*H]
#define OFF_BUF2 (2 * GB_B * GB_H)      // [2][B*H]
#define OFF_FLAGS (4 * GB_B * GB_H)     // 256 flags, 32 words apart
#define FLAG_STRIDE 32
#define OFF_GEN (OFF_FLAGS + NWG * FLAG_STRIDE)
#define WS_WORDS (OFF_GEN + 32)

__global__ void gru_init(const float* __restrict__ h0, float* __restrict__ ws) {
  int i = blockIdx.x * blockDim.x + threadIdx.x;
  if (i < GB_B * GB_H) {
    ws[OFF_BUF1 + i] = h0[i];                       // layer-1 h state, buf 0
  } else if (i < 2 * GB_B * GB_H) {
    ws[OFF_BUF2 + (i - GB_B * GB_H)] = h0[i];       // layer-2 h state, buf 0
  } else if (i < 2 * GB_B * GB_H + NWG * FLAG_STRIDE + 32) {
    ((unsigned*)ws)[OFF_FLAGS + (i - 2 * GB_B * GB_H)] = 0u;  // flags + gen
  }
}

__global__ __launch_bounds__(NTHR, 1) void gru_persist(
    const float* __restrict__ x,
    const float* __restrict__ w_ih, const float* __restrict__ w_hh,
    const float* __restrict__ b_ih, const float* __restrict__ b_hh,
    float* __restrict__ out, float* __restrict__ ws) {
  __shared__ float part[8][12][GB_B];  // 24 KB

  const int tid = threadIdx.x;
  const int lane = tid & 63;                       // batch row
  const int wg = blockIdx.x;
  const int layer = wg >> 7;                       // 0 or 1
  const int j0 = (wg & 127) << 2;                  // 4 hidden cols per WG
  const int wave = __builtin_amdgcn_readfirstlane(tid >> 6);
  const int side = wave >> 2;                      // 0 = input-side, 1 = hidden-side
  const int kbase = (wave & 3) << 7;               // K-quarter * 128

  float* buf1 = ws + OFF_BUF1;
  float* buf2 = ws + OFF_BUF2;
  unsigned* flags = (unsigned*)(ws + OFF_FLAGS);
  unsigned* gen = (unsigned*)(ws + OFF_GEN);

  const float* Wmat = (side ? w_hh : w_ih) + (size_t)layer * GB_G * GB_K;
  const float* bi = b_ih + layer * GB_G;
  const float* bh = b_hh + layer * GB_G;

  for (int s = 0; s <= GB_T; ++s) {
    const int t = layer ? s - 1 : s;
    const bool active = layer ? (s >= 1) : (s < GB_T);

    if (active) {
      const float* Abase;
      if (layer == 0)
        Abase = side ? (buf1 + (t & 1) * (GB_B * GB_H))
                     : (x + (size_t)t * GB_B * GB_K);
      else
        Abase = side ? (buf2 + (t & 1) * (GB_B * GB_H))
                     : (buf1 + ((t + 1) & 1) * (GB_B * GB_H));  // out1[t]
      const float* Arow = Abase + lane * GB_K + kbase;

      float acc[12];
#pragma unroll
      for (int c = 0; c < 12; ++c) acc[c] = 0.f;

      for (int k0 = 0; k0 < 128; k0 += 4) {
        const float4 a = *(const float4*)(Arow + k0);
#pragma unroll
        for (int gate = 0; gate < 3; ++gate) {
#pragma unroll
          for (int jj = 0; jj < 4; ++jj) {
            const float* wr =
                Wmat + (size_t)(gate * GB_H + j0 + jj) * GB_K + kbase + k0;
            float v = acc[gate * 4 + jj];
            v = fmaf(a.x, wr[0], v);
            v = fmaf(a.y, wr[1], v);
            v = fmaf(a.z, wr[2], v);
            v = fmaf(a.w, wr[3], v);
            acc[gate * 4 + jj] = v;
          }
        }
      }
#pragma unroll
      for (int c = 0; c < 12; ++c) part[wave][c][lane] = acc[c];
    }
    __syncthreads();

    if (active && wave < 4) {  // epilogue: wave w2 handles j = j0 + w2
      const int j = j0 + wave;
      float X[3], Hs[3];
#pragma unroll
      for (int gate = 0; gate < 3; ++gate) {
        const int c = gate * 4 + wave;
        X[gate] = part[0][c][lane] + part[1][c][lane] + part[2][c][lane] +
                  part[3][c][lane] + bi[gate * GB_H + j];
        Hs[gate] = part[4][c][lane] + part[5][c][lane] + part[6][c][lane] +
                   part[7][c][lane] + bh[gate * GB_H + j];
      }
      const float r = 1.f / (1.f + __expf(-(X[0] + Hs[0])));
      const float z = 1.f / (1.f + __expf(-(X[1] + Hs[1])));
      const float n = tanhf(X[2] + r * Hs[2]);
      float* bufl = layer ? buf2 : buf1;
      const int cur = t & 1;
      const float hold = bufl[cur * (GB_B * GB_H) + lane * GB_H + j];
      const float hnew = (1.f - z) * n + z * hold;
      bufl[(cur ^ 1) * (GB_B * GB_H) + lane * GB_H + j] = hnew;
      if (layer) out[((size_t)t * GB_B + lane) * GB_H + j] = hnew;
    }

    // ---- grid barrier (flag per WG, WG0 aggregates, gen broadcast) ----
    __syncthreads();  // drains vmcnt for all waves before the fence
    if (tid == 0) {
      __builtin_amdgcn_fence(__ATOMIC_RELEASE, "agent");
      __hip_atomic_store(&flags[wg * FLAG_STRIDE], (unsigned)(s + 1),
                         __ATOMIC_RELAXED, __HIP_MEMORY_SCOPE_AGENT);
    }
    if (wg == 0) {
      if (tid < NWG) {
        while (__hip_atomic_load(&flags[tid * FLAG_STRIDE], __ATOMIC_RELAXED,
                                 __HIP_MEMORY_SCOPE_AGENT) < (unsigned)(s + 1))
          __builtin_amdgcn_s_sleep(2);
      }
      __syncthreads();
      if (tid == 0) {
        __builtin_amdgcn_fence(__ATOMIC_ACQ_REL, "agent");
        __hip_atomic_store(gen, (unsigned)(s + 1), __ATOMIC_RELAXED,
                           __HIP_MEMORY_SCOPE_AGENT);
      }
    }
    if (tid == 0) {
      while (__hip_atomic_load(gen, __ATOMIC_RELAXED,
                               __HIP_MEMORY_SCOPE_AGENT) < (unsigned)(s + 1))
        __builtin_amdgcn_s_sleep(2);
      __builtin_amdgcn_fence(__ATOMIC_ACQUIRE, "agent");
    }
    __syncthreads();
  }
}

extern "C" void kernel_launch(void* const* d_in, const int* in_sizes, int n_in,
                              void* d_out, int out_size, void* d_ws,
                              size_t ws_size, hipStream_t stream) {
  const float* x = (const float*)d_in[0];
  const float* h0 = (const float*)d_in[1];
  const float* w_ih = (const float*)d_in[2];
  const float* w_hh = (const float*)d_in[3];
  const float* b_ih = (const float*)d_in[4];
  const float* b_hh = (const float*)d_in[5];
  float* out = (float*)d_out;
  float* ws = (float*)d_ws;

  const int init_elems = 2 * GB_B * GB_H + NWG * FLAG_STRIDE + 32;
  gru_init<<<(init_elems + 255) / 256, 256, 0, stream>>>(h0, ws);

  void* args[] = {(void*)&x,    (void*)&w_ih, (void*)&w_hh, (void*)&b_ih,
                  (void*)&b_hh, (void*)&out,  (void*)&ws};
  hipLaunchCooperativeKernel((const void*)gru_persist, dim3(NWG), dim3(NTHR),
                             args, 0, stream);
}

// Round 2
// 13228.548 us; speedup vs baseline: 1.2091x; 1.2091x over previous
//
#include <hip/hip_runtime.h>

// ---------------------------------------------------------------------------
// 2-layer GRU, T=512, B=64, I=H=512, fp32. Persistent cooperative kernel:
// 256 WGs (1/CU) x 512 threads, layers wavefront-pipelined (513 grid-steps).
// Round 2: fence-free design. Cross-XCD-coherent data (h buffers, flags) is
// accessed via explicit sc0 sc1 loads/stores (bypass incoherent L1/L2);
// everything else (weights, x) uses normal cached loads and stays hot in
// L1/sL1/L2 across steps because we never invalidate. One-round all-to-all
// flag barrier. Own-column h history kept in registers.
// ---------------------------------------------------------------------------

#define GB_B 64
#define GB_H 512
#define GB_K 512
#define GB_G 1536
#define GB_T 512
#define NWG 256
#define NTHR 512

// float-word offsets inside ws
#define OFF_BUF1 0                       // [2][B*H] layer-1 h ring
#define OFF_BUF2 (2 * GB_B * GB_H)      // [2][B*H] layer-2 h ring
#define OFF_FLAGS (4 * GB_B * GB_H)     // 256 flags, 32 dwords apart
#define FLAG_STRIDE 32

// ---- device-coherent (cross-XCD) access helpers: bypass L1+L2 -------------
__device__ __forceinline__ void st_coh_f1(float* p, float v) {
  asm volatile("global_store_dword %0, %1, off sc0 sc1" ::"v"(p), "v"(v)
               : "memory");
}
__device__ __forceinline__ void st_coh_u32(unsigned* p, unsigned v) {
  asm volatile("global_store_dword %0, %1, off sc0 sc1" ::"v"(p), "v"(v)
               : "memory");
}
__device__ __forceinline__ unsigned ld_coh_u32(const unsigned* p) {
  unsigned r;
  asm volatile("global_load_dword %0, %1, off sc0 sc1\n\ts_waitcnt vmcnt(0)"
               : "=v"(r)
               : "v"(p)
               : "memory");
  return r;
}
// 16B coherent load, NO wait inside — caller manages vmcnt.
#define LDC(dst, base, OFFS)                                              \
  asm volatile("global_load_dwordx4 %0, %1, off offset:" OFFS " sc0 sc1" \
               : "=v"(dst)                                                \
               : "v"(base))

__global__ void gru_init(const float* __restrict__ h0, float* __restrict__ ws) {
  int i = blockIdx.x * blockDim.x + threadIdx.x;
  if (i < 2 * GB_B * GB_H) {
    // buf1 slot0 = h0 layer 0 ; buf2 slot0 = h0 layer 1
    int layer = i / (GB_B * GB_H);
    int r = i % (GB_B * GB_H);
    st_coh_f1(ws + (layer ? OFF_BUF2 : OFF_BUF1) + r, h0[i]);
  } else if (i < 2 * GB_B * GB_H + NWG * FLAG_STRIDE) {
    unsigned* fl = (unsigned*)(ws + OFF_FLAGS);
    st_coh_u32(&fl[i - 2 * GB_B * GB_H], 0u);
  }
}

__global__ __launch_bounds__(NTHR, 2) void gru_persist(
    const float* __restrict__ x, const float* __restrict__ h0,
    const float* __restrict__ w_ih, const float* __restrict__ w_hh,
    const float* __restrict__ b_ih, const float* __restrict__ b_hh,
    float* __restrict__ out, float* __restrict__ ws) {
  __shared__ float part[8][12][GB_B];  // 24 KB

  const int tid = threadIdx.x;
  const int lane = tid & 63;  // batch row
  const int wg = blockIdx.x;
  const int layer = wg >> 7;       // 0 or 1
  const int j0 = (wg & 127) << 2;  // 4 hidden cols per WG
  const int wave = __builtin_amdgcn_readfirstlane(tid >> 6);
  const int side = wave >> 2;         // 0 = input-side, 1 = hidden-side
  const int kbase = (wave & 3) << 7;  // K-quarter * 128

  float* buf1 = ws + OFF_BUF1;
  float* buf2 = ws + OFF_BUF2;
  unsigned* flags = (unsigned*)(ws + OFF_FLAGS);

  const float* Wmat = (side ? w_hh : w_ih) + (size_t)layer * GB_G * GB_K;

  // Epilogue-thread state: biases and own-column h history in registers.
  float bx[3] = {0.f, 0.f, 0.f}, bh[3] = {0.f, 0.f, 0.f};
  float hreg = 0.f;
  if (wave < 4) {
    const int j = j0 + wave;
#pragma unroll
    for (int g = 0; g < 3; ++g) {
      bx[g] = b_ih[layer * GB_G + g * GB_H + j];
      bh[g] = b_hh[layer * GB_G + g * GB_H + j];
    }
    hreg = h0[((size_t)layer * GB_B + lane) * GB_H + j];
  }

  for (int s = 0; s <= GB_T; ++s) {
    const int t = layer ? s - 1 : s;
    const bool active = layer ? (s >= 1) : (s < GB_T);

    if (active) {
      float acc[12];
#pragma unroll
      for (int c = 0; c < 12; ++c) acc[c] = 0.f;

      const bool coh = (layer != 0) || (side != 0);  // reads a ws h-buffer
      if (coh) {
        const float* Abase;
        if (layer == 0)
          Abase = buf1 + (t & 1) * (GB_B * GB_H);
        else
          Abase = side ? (buf2 + (t & 1) * (GB_B * GB_H))
                       : (buf1 + ((t + 1) & 1) * (GB_B * GB_H));  // out1[t]
        const float* Arow = Abase + lane * GB_K + kbase;

        float4 Ab[32];
        LDC(Ab[0], Arow, "0");     LDC(Ab[1], Arow, "16");
        LDC(Ab[2], Arow, "32");    LDC(Ab[3], Arow, "48");
        LDC(Ab[4], Arow, "64");    LDC(Ab[5], Arow, "80");
        LDC(Ab[6], Arow, "96");    LDC(Ab[7], Arow, "112");
        LDC(Ab[8], Arow, "128");   LDC(Ab[9], Arow, "144");
        LDC(Ab[10], Arow, "160");  LDC(Ab[11], Arow, "176");
        LDC(Ab[12], Arow, "192");  LDC(Ab[13], Arow, "208");
        LDC(Ab[14], Arow, "224");  LDC(Ab[15], Arow, "240");
        LDC(Ab[16], Arow, "256");  LDC(Ab[17], Arow, "272");
        LDC(Ab[18], Arow, "288");  LDC(Ab[19], Arow, "304");
        LDC(Ab[20], Arow, "320");  LDC(Ab[21], Arow, "336");
        LDC(Ab[22], Arow, "352");  LDC(Ab[23], Arow, "368");
        LDC(Ab[24], Arow, "384");  LDC(Ab[25], Arow, "400");
        LDC(Ab[26], Arow, "416");  LDC(Ab[27], Arow, "432");
        LDC(Ab[28], Arow, "448");  LDC(Ab[29], Arow, "464");
        LDC(Ab[30], Arow, "480");  LDC(Ab[31], Arow, "496");

#pragma unroll
        for (int blk = 0; blk < 4; ++blk) {
          if (blk == 0)
            asm volatile("s_waitcnt vmcnt(24)" ::: "memory");
          else if (blk == 1)
            asm volatile("s_waitcnt vmcnt(16)" ::: "memory");
          else if (blk == 2)
            asm volatile("s_waitcnt vmcnt(8)" ::: "memory");
          else
            asm volatile("s_waitcnt vmcnt(0)" ::: "memory");
          __builtin_amdgcn_sched_barrier(0);
#pragma unroll
          for (int u = 0; u < 8; ++u) {
            const float4 a = Ab[blk * 8 + u];
            const int k0 = blk * 32 + u * 4;
#pragma unroll
            for (int gate = 0; gate < 3; ++gate) {
#pragma unroll
              for (int jj = 0; jj < 4; ++jj) {
                const float* wr =
                    Wmat + (size_t)(gate * GB_H + j0 + jj) * GB_K + kbase + k0;
                float v = acc[gate * 4 + jj];
                v = fmaf(a.x, wr[0], v);
                v = fmaf(a.y, wr[1], v);
                v = fmaf(a.z, wr[2], v);
                v = fmaf(a.w, wr[3], v);
                acc[gate * 4 + jj] = v;
              }
            }
          }
        }
      } else {
        // layer-1 input side: x is read-only, use normal cached loads.
        const float* Arow = x + (size_t)t * GB_B * GB_K + lane * GB_K + kbase;
        for (int k0 = 0; k0 < 128; k0 += 4) {
          const float4 a = *(const float4*)(Arow + k0);
#pragma unroll
          for (int gate = 0; gate < 3; ++gate) {
#pragma unroll
            for (int jj = 0; jj < 4; ++jj) {
              const float* wr =
                  Wmat + (size_t)(gate * GB_H + j0 + jj) * GB_K + kbase + k0;
              float v = acc[gate * 4 + jj];
              v = fmaf(a.x, wr[0], v);
              v = fmaf(a.y, wr[1], v);
              v = fmaf(a.z, wr[2], v);
              v = fmaf(a.w, wr[3], v);
              acc[gate * 4 + jj] = v;
            }
          }
        }
      }
#pragma unroll
      for (int c = 0; c < 12; ++c) part[wave][c][lane] = acc[c];
    }
    __syncthreads();

    if (active && wave < 4) {  // epilogue: wave w handles col j = j0 + w
      const int j = j0 + wave;
      float X[3], Hs[3];
#pragma unroll
      for (int gate = 0; gate < 3; ++gate) {
        const int c = gate * 4 + wave;
        X[gate] = part[0][c][lane] + part[1][c][lane] + part[2][c][lane] +
                  part[3][c][lane] + bx[gate];
        Hs[gate] = part[4][c][lane] + part[5][c][lane] + part[6][c][lane] +
                   part[7][c][lane] + bh[gate];
      }
      const float r = 1.f / (1.f + __expf(-(X[0] + Hs[0])));
      const float z = 1.f / (1.f + __expf(-(X[1] + Hs[1])));
      const float n = tanhf(X[2] + r * Hs[2]);
      const float hnew = (1.f - z) * n + z * hreg;
      hreg = hnew;
      float* bufl = layer ? buf2 : buf1;
      st_coh_f1(bufl + ((t & 1) ^ 1) * (GB_B * GB_H) + lane * GB_H + j, hnew);
      if (layer) out[((size_t)t * GB_B + lane) * GB_H + j] = hnew;
    }

    // ---- one-round all-to-all grid barrier (fence-free, sc1 flags) ----
    if (s < GB_T) {
      asm volatile("s_waitcnt vmcnt(0)" ::: "memory");  // drain own h stores
      __syncthreads();  // all waves of WG done (incl. their stores)
      if (tid == 0) st_coh_u32(&flags[wg * FLAG_STRIDE], (unsigned)(s + 1));
      if (tid < NWG) {
        const unsigned tgt = (unsigned)(s + 1);
        while (ld_coh_u32(&flags[tid * FLAG_STRIDE]) < tgt) {
        }
      }
      __syncthreads();
    }
  }
}

extern "C" void kernel_launch(void* const* d_in, const int* in_sizes, int n_in,
                              void* d_out, int out_size, void* d_ws,
                              size_t ws_size, hipStream_t stream) {
  const float* x = (const float*)d_in[0];
  const float* h0 = (const float*)d_in[1];
  const float* w_ih = (const float*)d_in[2];
  const float* w_hh = (const float*)d_in[3];
  const float* b_ih = (const float*)d_in[4];
  const float* b_hh = (const float*)d_in[5];
  float* out = (float*)d_out;
  float* ws = (float*)d_ws;

  const int init_elems = 2 * GB_B * GB_H + NWG * FLAG_STRIDE;
  gru_init<<<(init_elems + 255) / 256, 256, 0, stream>>>(h0, ws);

  void* args[] = {(void*)&x,    (void*)&h0,   (void*)&w_ih, (void*)&w_hh,
                  (void*)&b_ih, (void*)&b_hh, (void*)&out,  (void*)&ws};
  hipLaunchCooperativeKernel((const void*)gru_persist, dim3(NWG), dim3(NTHR),
                             args, 0, stream);
}

// Round 4
// 11518.005 us; speedup vs baseline: 1.3887x; 1.1485x over previous
//
#include <hip/hip_runtime.h>

// ---------------------------------------------------------------------------
// 2-layer GRU, T=512, B=64, I=H=512, fp32. Persistent cooperative kernel:
// 256 WGs (1/CU) x 512 threads, layers wavefront-pipelined (513 grid-steps).
// Round 4 (= round 3 + compile fix):
//  - native ext_vector f32x4 for all inline-asm 16B operands (float4 struct
//    cannot be an asm input operand -> "indirect register inputs" error)
//  - A-loads in 2 chunks of 16 quads (no register blowup / spills)
//  - weight row pointers hoisted out of the step loop (uniform/scalar)
//  - h/out stores transposed via LDS; single wave does dwordx4 stores
//  - barrier: wave 0 polls 4 flags/lane with s_sleep backoff
// Coherent (cross-XCD) data goes through sc0 sc1 loads/stores; weights and x
// use normal cached loads and stay hot in L1/L2 (never invalidated).
// ---------------------------------------------------------------------------

typedef float f32x4 __attribute__((ext_vector_type(4)));

#define GB_B 64
#define GB_H 512
#define GB_K 512
#define GB_G 1536
#define GB_T 512
#define NWG 256
#define NTHR 512

// float-word offsets inside ws
#define OFF_BUF1 0                     // [2][B*H] layer-1 h ring
#define OFF_BUF2 (2 * GB_B * GB_H)    // [2][B*H] layer-2 h ring
#define OFF_FLAGS (4 * GB_B * GB_H)   // 256 flags, 32 dwords (128 B) apart
#define FLAG_STRIDE 32

// ---- device-coherent (cross-XCD) access helpers ---------------------------
__device__ __forceinline__ void st_coh_f4(float* p, f32x4 v) {
  asm volatile("global_store_dwordx4 %0, %1, off sc0 sc1" ::"v"(p), "v"(v)
               : "memory");
}
__device__ __forceinline__ void st_coh_f1(float* p, float v) {
  asm volatile("global_store_dword %0, %1, off sc0 sc1" ::"v"(p), "v"(v)
               : "memory");
}
__device__ __forceinline__ void st_coh_u32(unsigned* p, unsigned v) {
  asm volatile("global_store_dword %0, %1, off sc0 sc1" ::"v"(p), "v"(v)
               : "memory");
}
// 16B coherent load, NO wait — caller manages vmcnt.
#define LDC(dst, base, OFFS)                                             \
  asm volatile("global_load_dwordx4 %0, %1, off offset:" OFFS " sc0 sc1" \
               : "=v"(dst)                                               \
               : "v"(base))
// 4B coherent load, NO wait.
#define LDCF(dst, addr)                                  \
  asm volatile("global_load_dword %0, %1, off sc0 sc1" \
               : "=v"(dst)                               \
               : "v"(addr))

__global__ void gru_init(const float* __restrict__ h0, float* __restrict__ ws) {
  int i = blockIdx.x * blockDim.x + threadIdx.x;
  if (i < 2 * GB_B * GB_H) {
    int layer = i / (GB_B * GB_H);
    int r = i % (GB_B * GB_H);
    st_coh_f1(ws + (layer ? OFF_BUF2 : OFF_BUF1) + r, h0[i]);
  } else if (i < 2 * GB_B * GB_H + NWG * FLAG_STRIDE) {
    unsigned* fl = (unsigned*)(ws + OFF_FLAGS);
    st_coh_u32(&fl[i - 2 * GB_B * GB_H], 0u);
  }
}

// 12-row FMA micro-tile: acc[r] += dot(a, Wrow[r][K0..K0+3])
__device__ __forceinline__ void fma12(const f32x4 a, const float* const* Wrow,
                                      float* acc, const int K0) {
#pragma unroll
  for (int r = 0; r < 12; ++r) {
    const float* wr = Wrow[r] + K0;
    float v = acc[r];
    v = fmaf(a.x, wr[0], v);
    v = fmaf(a.y, wr[1], v);
    v = fmaf(a.z, wr[2], v);
    v = fmaf(a.w, wr[3], v);
    acc[r] = v;
  }
}

__global__ __launch_bounds__(NTHR, 2) void gru_persist(
    const float* __restrict__ x, const float* __restrict__ h0,
    const float* __restrict__ w_ih, const float* __restrict__ w_hh,
    const float* __restrict__ b_ih, const float* __restrict__ b_hh,
    float* __restrict__ out, float* __restrict__ ws) {
  __shared__ float part[8][12][GB_B];  // 24 KB
  __shared__ float sh_h[GB_B][4];      // 1 KB transpose tile

  const int tid = threadIdx.x;
  const int lane = tid & 63;  // batch row
  const int wg = blockIdx.x;
  const int layer = wg >> 7;       // 0 or 1
  const int j0 = (wg & 127) << 2;  // 4 hidden cols per WG
  const int wave = __builtin_amdgcn_readfirstlane(tid >> 6);
  const int side = wave >> 2;         // 0 = input-side, 1 = hidden-side
  const int kbase = (wave & 3) << 7;  // K-quarter * 128

  float* buf1 = ws + OFF_BUF1;
  float* buf2 = ws + OFF_BUF2;
  unsigned* flags = (unsigned*)(ws + OFF_FLAGS);

  // Step-invariant weight row pointers (all uniform -> scalar regs).
  const float* Wmat = (side ? w_hh : w_ih) + (size_t)layer * GB_G * GB_K;
  const float* Wrow[12];
#pragma unroll
  for (int gate = 0; gate < 3; ++gate)
#pragma unroll
    for (int jj = 0; jj < 4; ++jj)
      Wrow[gate * 4 + jj] =
          Wmat + (size_t)(gate * GB_H + j0 + jj) * GB_K + kbase;

  // Epilogue state: biases + own-column running h in registers (waves 0-3).
  float bx[3] = {0.f, 0.f, 0.f}, bh[3] = {0.f, 0.f, 0.f};
  float hreg = 0.f;
  if (wave < 4) {
    const int j = j0 + wave;
#pragma unroll
    for (int g = 0; g < 3; ++g) {
      bx[g] = b_ih[layer * GB_G + g * GB_H + j];
      bh[g] = b_hh[layer * GB_G + g * GB_H + j];
    }
    hreg = h0[((size_t)layer * GB_B + lane) * GB_H + j];
  }

  // Wave-0 poll pointers (4 flags per lane), step-invariant.
  const unsigned* fp0 = flags + (lane + 0) * FLAG_STRIDE;
  const unsigned* fp1 = flags + (lane + 64) * FLAG_STRIDE;
  const unsigned* fp2 = flags + (lane + 128) * FLAG_STRIDE;
  const unsigned* fp3 = flags + (lane + 192) * FLAG_STRIDE;

  for (int s = 0; s <= GB_T; ++s) {
    const int t = layer ? s - 1 : s;
    const bool active = layer ? (s >= 1) : (s < GB_T);

    if (active) {
      float acc[12];
#pragma unroll
      for (int c = 0; c < 12; ++c) acc[c] = 0.f;

      const bool coh = (layer != 0) || (side != 0);  // reads a ws h-buffer
      if (coh) {
        const float* Abase;
        if (layer == 0)
          Abase = buf1 + (t & 1) * (GB_B * GB_H);
        else
          Abase = side ? (buf2 + (t & 1) * (GB_B * GB_H))
                       : (buf1 + ((t + 1) & 1) * (GB_B * GB_H));  // out1[t]
        const float* Arow = Abase + lane * GB_K + kbase;

        f32x4 q[16];
        // ---- chunk 0: floats 0..63 ----
        LDC(q[0], Arow, "0");     LDC(q[1], Arow, "16");
        LDC(q[2], Arow, "32");    LDC(q[3], Arow, "48");
        LDC(q[4], Arow, "64");    LDC(q[5], Arow, "80");
        LDC(q[6], Arow, "96");    LDC(q[7], Arow, "112");
        LDC(q[8], Arow, "128");   LDC(q[9], Arow, "144");
        LDC(q[10], Arow, "160");  LDC(q[11], Arow, "176");
        LDC(q[12], Arow, "192");  LDC(q[13], Arow, "208");
        LDC(q[14], Arow, "224");  LDC(q[15], Arow, "240");
        asm volatile("s_waitcnt vmcnt(0)" ::: "memory");
        __builtin_amdgcn_sched_barrier(0);
#pragma unroll
        for (int u = 0; u < 16; ++u) fma12(q[u], Wrow, acc, u * 4);

        // ---- chunk 1: floats 64..127 ----
        LDC(q[0], Arow, "256");   LDC(q[1], Arow, "272");
        LDC(q[2], Arow, "288");   LDC(q[3], Arow, "304");
        LDC(q[4], Arow, "320");   LDC(q[5], Arow, "336");
        LDC(q[6], Arow, "352");   LDC(q[7], Arow, "368");
        LDC(q[8], Arow, "384");   LDC(q[9], Arow, "400");
        LDC(q[10], Arow, "416");  LDC(q[11], Arow, "432");
        LDC(q[12], Arow, "448");  LDC(q[13], Arow, "464");
        LDC(q[14], Arow, "480");  LDC(q[15], Arow, "496");
        asm volatile("s_waitcnt vmcnt(0)" ::: "memory");
        __builtin_amdgcn_sched_barrier(0);
#pragma unroll
        for (int u = 0; u < 16; ++u) fma12(q[u], Wrow, acc, 64 + u * 4);
      } else {
        // layer-1 input side: x is read-only, normal cached loads.
        const float* Arow = x + (size_t)t * GB_B * GB_K + lane * GB_K + kbase;
#pragma unroll
        for (int u = 0; u < 32; ++u) {
          const f32x4 a = *(const f32x4*)(Arow + u * 4);
          fma12(a, Wrow, acc, u * 4);
        }
      }
#pragma unroll
      for (int c = 0; c < 12; ++c) part[wave][c][lane] = acc[c];
    }
    __syncthreads();

    if (active && wave < 4) {  // epilogue: wave w handles col j = j0 + w
      float X[3], Hs[3];
#pragma unroll
      for (int gate = 0; gate < 3; ++gate) {
        const int c = gate * 4 + wave;
        X[gate] = part[0][c][lane] + part[1][c][lane] + part[2][c][lane] +
                  part[3][c][lane] + bx[gate];
        Hs[gate] = part[4][c][lane] + part[5][c][lane] + part[6][c][lane] +
                   part[7][c][lane] + bh[gate];
      }
      const float r = 1.f / (1.f + __expf(-(X[0] + Hs[0])));
      const float z = 1.f / (1.f + __expf(-(X[1] + Hs[1])));
      const float n = tanhf(X[2] + r * Hs[2]);
      const float hnew = (1.f - z) * n + z * hreg;
      hreg = hnew;
      sh_h[lane][wave] = hnew;
    }
    __syncthreads();

    // Wave 0 stores the 64x4 h tile as one dwordx4 per row, then runs the
    // grid barrier while other waves wait at the trailing __syncthreads.
    if (tid < 64) {
      if (active) {
        const f32x4 hv = *(const f32x4*)&sh_h[lane][0];
        float* bufl = layer ? buf2 : buf1;
        st_coh_f4(bufl + ((t & 1) ^ 1) * (GB_B * GB_H) + lane * GB_H + j0, hv);
        if (layer)
          *(f32x4*)(out + ((size_t)t * GB_B + lane) * GB_H + j0) = hv;
      }
      if (s < GB_T) {
        asm volatile("s_waitcnt vmcnt(0)" ::: "memory");  // drain h stores
        if (tid == 0) st_coh_u32(&flags[wg * FLAG_STRIDE], (unsigned)(s + 1));
        const unsigned tgt = (unsigned)(s + 1);
        for (;;) {
          unsigned f0, f1, f2, f3;
          LDCF(f0, fp0);
          LDCF(f1, fp1);
          LDCF(f2, fp2);
          LDCF(f3, fp3);
          asm volatile("s_waitcnt vmcnt(0)" ::: "memory");
          const int ok =
              (f0 >= tgt) && (f1 >= tgt) && (f2 >= tgt) && (f3 >= tgt);
          if (__all(ok)) break;
          __builtin_amdgcn_s_sleep(1);
        }
      }
    }
    __syncthreads();
  }
}

extern "C" void kernel_launch(void* const* d_in, const int* in_sizes, int n_in,
                              void* d_out, int out_size, void* d_ws,
                              size_t ws_size, hipStream_t stream) {
  const float* x = (const float*)d_in[0];
  const float* h0 = (const float*)d_in[1];
  const float* w_ih = (const float*)d_in[2];
  const float* w_hh = (const float*)d_in[3];
  const float* b_ih = (const float*)d_in[4];
  const float* b_hh = (const float*)d_in[5];
  float* out = (float*)d_out;
  float* ws = (float*)d_ws;

  const int init_elems = 2 * GB_B * GB_H + NWG * FLAG_STRIDE;
  gru_init<<<(init_elems + 255) / 256, 256, 0, stream>>>(h0, ws);

  void* args[] = {(void*)&x,    (void*)&h0,   (void*)&w_ih, (void*)&w_hh,
                  (void*)&b_ih, (void*)&b_hh, (void*)&out,  (void*)&ws};
  (void)hipLaunchCooperativeKernel((const void*)gru_persist, dim3(NWG),
                                   dim3(NTHR), args, 0, stream);
}

// Round 5
// 7390.014 us; speedup vs baseline: 2.1644x; 1.5586x over previous
//
#include <hip/hip_runtime.h>

// ---------------------------------------------------------------------------
// 2-layer GRU, T=512, B=64, I=H=512, fp32. Persistent cooperative kernel:
// 256 WGs (1/CU) x 512 threads, layers wavefront-pipelined (513 grid-steps).
// Round 5: L2-cached h broadcast via FRESH ADDRESSES.
//  - h1_t stored to a T-deep ring in ws (write-once addresses); h2_t stored
//    directly to out[t]. Consumers use NORMAL CACHED loads (L2 shares the
//    broadcast across the 32 WGs of an XCD) — safe because every slab address
//    is never read before it is written in this dispatch, and each WG
//    executes one agent-scope acquire fence (buffer_inv) at kernel entry to
//    drop stale L1/L2 lines from poison / previous graph replays.
//  - producers store h via sc0 sc1 (write-through to coherence point).
//  - packed flags (256 x 4B = 8 cache lines): every WG's wave 0 polls all
//    flags with one dwordx4 per lane. One-round-trip barrier, low traffic.
// ---------------------------------------------------------------------------

typedef float f32x4 __attribute__((ext_vector_type(4)));
typedef unsigned u32x4 __attribute__((ext_vector_type(4)));

#define GB_B 64
#define GB_H 512
#define GB_K 512
#define GB_G 1536
#define GB_T 512
#define NWG 256
#define NTHR 512
#define BH (GB_B * GB_H)  // one step-slab: 32768 floats = 131 KB

// float-word offsets inside ws
#define OFF_FLAGS 0        // 256 packed u32 flags (1 KB), page-padded
#define OFF_RING1 1024     // 512 slabs of BH floats = 67.1 MB
// total ws need = (1024 + 512*32768)*4 B ~= 67.2 MB

// ---- coherence helpers ----------------------------------------------------
__device__ __forceinline__ void st_coh_f4(float* p, f32x4 v) {
  asm volatile("global_store_dwordx4 %0, %1, off sc0 sc1" ::"v"(p), "v"(v)
               : "memory");
}
__device__ __forceinline__ void st_coh_u32(unsigned* p, unsigned v) {
  asm volatile("global_store_dword %0, %1, off sc0 sc1" ::"v"(p), "v"(v)
               : "memory");
}
// 16B coherent load of 4 packed flags, NO wait — caller manages vmcnt.
#define LDC4U(dst, addr)                                  \
  asm volatile("global_load_dwordx4 %0, %1, off sc0 sc1" \
               : "=v"(dst)                                \
               : "v"(addr))

__global__ void gru_init(float* __restrict__ ws) {
  unsigned* fl = (unsigned*)(ws + OFF_FLAGS);
  st_coh_u32(&fl[threadIdx.x], 0u);  // 1 block x 256 threads
}

// 12-row FMA micro-tile: acc[r] += dot(a, Wrow[r][K0..K0+3])
__device__ __forceinline__ void fma12(const f32x4 a, const float* const* Wrow,
                                      float* acc, const int K0) {
#pragma unroll
  for (int r = 0; r < 12; ++r) {
    const float* wr = Wrow[r] + K0;
    float v = acc[r];
    v = fmaf(a.x, wr[0], v);
    v = fmaf(a.y, wr[1], v);
    v = fmaf(a.z, wr[2], v);
    v = fmaf(a.w, wr[3], v);
    acc[r] = v;
  }
}

__global__ __launch_bounds__(NTHR, 2) void gru_persist(
    const float* __restrict__ x, const float* __restrict__ h0,
    const float* __restrict__ w_ih, const float* __restrict__ w_hh,
    const float* __restrict__ b_ih, const float* __restrict__ b_hh,
    float* __restrict__ out, float* __restrict__ ws) {
  __shared__ float part[8][12][GB_B];  // 24 KB
  __shared__ float sh_h[GB_B][4];      // 1 KB transpose tile

  const int tid = threadIdx.x;
  const int lane = tid & 63;  // batch row
  const int wg = blockIdx.x;
  const int layer = wg >> 7;       // 0 = first GRU layer, 1 = second
  const int j0 = (wg & 127) << 2;  // 4 hidden cols per WG
  const int wave = __builtin_amdgcn_readfirstlane(tid >> 6);
  const int side = wave >> 2;         // 0 = input-side, 1 = hidden-side
  const int kbase = (wave & 3) << 7;  // K-quarter * 128

  unsigned* flags = (unsigned*)(ws + OFF_FLAGS);
  float* ring1 = ws + OFF_RING1;  // h1_t slabs, t = 0..511

  // Step-invariant weight row pointers (uniform -> scalar regs).
  const float* Wmat = (side ? w_hh : w_ih) + (size_t)layer * GB_G * GB_K;
  const float* Wrow[12];
#pragma unroll
  for (int gate = 0; gate < 3; ++gate)
#pragma unroll
    for (int jj = 0; jj < 4; ++jj)
      Wrow[gate * 4 + jj] =
          Wmat + (size_t)(gate * GB_H + j0 + jj) * GB_K + kbase;

  // Epilogue state: biases + own-column running h in registers (waves 0-3).
  float bx[3] = {0.f, 0.f, 0.f}, bh[3] = {0.f, 0.f, 0.f};
  float hreg = 0.f;
  if (wave < 4) {
    const int j = j0 + wave;
#pragma unroll
    for (int g = 0; g < 3; ++g) {
      bx[g] = b_ih[layer * GB_G + g * GB_H + j];
      bh[g] = b_hh[layer * GB_G + g * GB_H + j];
    }
    hreg = h0[((size_t)layer * GB_B + lane) * GB_H + j];
  }

  // Drop stale L1/L2 lines (poison / previous replay) before any cached read
  // of ring1/out. Reads above (weights, biases, h0, x) are of immutable
  // buffers and are safe either way.
  __builtin_amdgcn_fence(__ATOMIC_ACQUIRE, "agent");
  __syncthreads();

  for (int s = 0; s <= GB_T; ++s) {
    const int t = layer ? s - 1 : s;
    const bool active = layer ? (s >= 1) : (s < GB_T);

    if (active) {
      // A-operand base: all mutable slabs are fresh-address -> cached loads.
      const float* Abase;
      if (layer == 0)
        Abase = side ? (t ? ring1 + (size_t)(t - 1) * BH : h0)
                     : (x + (size_t)t * BH);
      else
        Abase = side ? (t ? out + (size_t)(t - 1) * BH : h0 + BH)
                     : (ring1 + (size_t)t * BH);
      const float* Arow = Abase + lane * GB_K + kbase;

      float acc[12];
#pragma unroll
      for (int c = 0; c < 12; ++c) acc[c] = 0.f;
#pragma unroll
      for (int u = 0; u < 32; ++u) {
        const f32x4 a = *(const f32x4*)(Arow + u * 4);
        fma12(a, Wrow, acc, u * 4);
      }
#pragma unroll
      for (int c = 0; c < 12; ++c) part[wave][c][lane] = acc[c];
    }
    __syncthreads();

    if (active && wave < 4) {  // epilogue: wave w handles col j = j0 + w
      float X[3], Hs[3];
#pragma unroll
      for (int gate = 0; gate < 3; ++gate) {
        const int c = gate * 4 + wave;
        X[gate] = part[0][c][lane] + part[1][c][lane] + part[2][c][lane] +
                  part[3][c][lane] + bx[gate];
        Hs[gate] = part[4][c][lane] + part[5][c][lane] + part[6][c][lane] +
                   part[7][c][lane] + bh[gate];
      }
      const float r = 1.f / (1.f + __expf(-(X[0] + Hs[0])));
      const float z = 1.f / (1.f + __expf(-(X[1] + Hs[1])));
      const float n = tanhf(X[2] + r * Hs[2]);
      const float hnew = (1.f - z) * n + z * hreg;
      hreg = hnew;
      sh_h[lane][wave] = hnew;
    }
    __syncthreads();

    // Wave 0: store the 64x4 h tile (write-through), then grid barrier.
    if (tid < 64) {
      if (active) {
        const f32x4 hv = *(const f32x4*)&sh_h[lane][0];
        float* dst = (layer ? out : ring1) + (size_t)t * BH;
        st_coh_f4(dst + lane * GB_H + j0, hv);
      }
      if (s < GB_T) {
        asm volatile("s_waitcnt vmcnt(0)" ::: "memory");  // h stores at L3
        if (tid == 0) st_coh_u32(&flags[wg], (unsigned)(s + 1));
        const unsigned tgt = (unsigned)(s + 1);
        const unsigned* fp = flags + lane * 4;
        for (;;) {
          u32x4 f;
          LDC4U(f, fp);
          asm volatile("s_waitcnt vmcnt(0)" ::: "memory");
          const int ok = (f.x >= tgt) && (f.y >= tgt) && (f.z >= tgt) &&
                         (f.w >= tgt);
          if (__all(ok)) break;
          __builtin_amdgcn_s_sleep(1);
        }
      }
    }
    __syncthreads();
  }
}

extern "C" void kernel_launch(void* const* d_in, const int* in_sizes, int n_in,
                              void* d_out, int out_size, void* d_ws,
                              size_t ws_size, hipStream_t stream) {
  const float* x = (const float*)d_in[0];
  const float* h0 = (const float*)d_in[1];
  const float* w_ih = (const float*)d_in[2];
  const float* w_hh = (const float*)d_in[3];
  const float* b_ih = (const float*)d_in[4];
  const float* b_hh = (const float*)d_in[5];
  float* out = (float*)d_out;
  float* ws = (float*)d_ws;

  gru_init<<<1, 256, 0, stream>>>(ws);

  void* args[] = {(void*)&x,    (void*)&h0,   (void*)&w_ih, (void*)&w_hh,
                  (void*)&b_ih, (void*)&b_hh, (void*)&out,  (void*)&ws};
  (void)hipLaunchCooperativeKernel((const void*)gru_persist, dim3(NWG),
                                   dim3(NTHR), args, 0, stream);
}